// Round 8
// baseline (313.548 us; speedup 1.0000x reference)
//
#include <hip/hip_runtime.h>
#include <math.h>

#define HEADS 16
#define EMB 1024
#define BATCH 4
#define SEQ 2048

typedef __bf16 bf16_t;
typedef __bf16 bf16x4 __attribute__((ext_vector_type(4)));
typedef __bf16 bf16x8 __attribute__((ext_vector_type(8)));
typedef float f32x4 __attribute__((ext_vector_type(4)));
typedef float f32x16 __attribute__((ext_vector_type(16)));
typedef unsigned int u32x4 __attribute__((ext_vector_type(4)));

__device__ __forceinline__ f32x16 mfma32(bf16x8 a, bf16x8 b, f32x16 c) {
    return __builtin_amdgcn_mfma_f32_32x32x16_bf16(a, b, c, 0, 0, 0);
}

__device__ __forceinline__ unsigned cvtpk(float lo, float hi) {
    unsigned r;
    asm("v_cvt_pk_bf16_f32 %0, %1, %2" : "=v"(r) : "v"(lo), "v"(hi));
    return r;
}

__device__ __forceinline__ void plswap(unsigned &a, unsigned &b) {
    asm volatile("v_permlane32_swap_b32 %0, %1" : "+v"(a), "+v"(b));
}

// Pack 16 per-lane P values (QK^T output layout) into the two PV A-fragments.
__device__ __forceinline__ void pack_p(const float* p, bf16x8& pa0, bf16x8& pa1) {
    unsigned w0 = cvtpk(p[0], p[1]),   w1 = cvtpk(p[2], p[3]);
    unsigned w2 = cvtpk(p[4], p[5]),   w3 = cvtpk(p[6], p[7]);
    plswap(w0, w2); plswap(w1, w3);
    unsigned w4 = cvtpk(p[8], p[9]),   w5 = cvtpk(p[10], p[11]);
    unsigned w6 = cvtpk(p[12], p[13]), w7 = cvtpk(p[14], p[15]);
    plswap(w4, w6); plswap(w5, w7);
    u32x4 ua = {w0, w1, w2, w3};
    u32x4 ub = {w4, w5, w6, w7};
    pa0 = __builtin_bit_cast(bf16x8, ua);
    pa1 = __builtin_bit_cast(bf16x8, ub);
}

// ---------------------------------------------------------------------------
// Per-batch masked-key count (as float).  Grid = BATCH, block = 256.
// ---------------------------------------------------------------------------
__global__ void nmask_kernel(const int* __restrict__ mask, float* __restrict__ nmaskf) {
    const int b = blockIdx.x;
    const int t = threadIdx.x;
    int cnt = 0;
    #pragma unroll
    for (int i = 0; i < SEQ / 256; ++i)
        cnt += (mask[b * SEQ + t + i * 256] == 0);
    #pragma unroll
    for (int d = 1; d < 64; d <<= 1) cnt += __shfl_xor(cnt, d);
    __shared__ int red[4];
    if ((t & 63) == 0) red[t >> 6] = cnt;
    __syncthreads();
    if (t == 0) nmaskf[b] = (float)(red[0] + red[1] + red[2] + red[3]);
}

// Wfc f32 -> bf16
__global__ void wconv_kernel(const float* __restrict__ w, bf16_t* __restrict__ wb, int n) {
    int i = (blockIdx.x * 256 + threadIdx.x) * 4;
    if (i < n) {
        float4 f = *(const float4*)(w + i);
        bf16x4 o;
        o[0] = (bf16_t)f.x; o[1] = (bf16_t)f.y; o[2] = (bf16_t)f.z; o[3] = (bf16_t)f.w;
        *(bf16x4*)(wb + i) = o;
    }
}

// ---------------------------------------------------------------------------
// Projections: per 64-row tile of ONE (b,h).  Writes:
//   q_hi/q_lo, k_hi/k_lo : [bh][l][64] bf16 (hi/lo split of fp32 result)
//   vt                   : [bh][64][SEQ] bf16 (transposed)
// K and V rows of MASKED keys are zeroed (score becomes exactly 0 ->
// p = exp(floor(0)) = 1, PV contribution 0; denominator corrected by nmask).
// ---------------------------------------------------------------------------
__global__ __launch_bounds__(256) void proj_kernel(
    const float* __restrict__ xq, const float* __restrict__ xk, const float* __restrict__ xv,
    const float* __restrict__ Wq, const float* __restrict__ bq,
    const float* __restrict__ Wk, const float* __restrict__ bk,
    const float* __restrict__ Wv, const float* __restrict__ bv,
    const int* __restrict__ mask,
    bf16_t* __restrict__ qh, bf16_t* __restrict__ ql,
    bf16_t* __restrict__ khp, bf16_t* __restrict__ klp,
    bf16_t* __restrict__ vt)
{
    __shared__ float Xs[64][68];   // Xs[d][l]
    __shared__ float Ws[64][68];   // Ws[d][e]

    const int t   = threadIdx.x;
    const int mat = blockIdx.y;
    const int bh  = blockIdx.x >> 5;
    const int l0  = (blockIdx.x & 31) * 64;
    const int b   = bh >> 4;
    const int hh  = bh & 15;

    const float* __restrict__ X    = (mat == 0) ? xq : (mat == 1) ? xk : xv;
    const float* __restrict__ W    = (mat == 0) ? Wq : (mat == 1) ? Wk : Wv;
    const float* __restrict__ bias = (mat == 0) ? bq : (mat == 1) ? bk : bv;

    #pragma unroll
    for (int i = 0; i < 4; ++i) {
        int c    = t + i * 256;
        int l    = c >> 4;
        int dblk = (c & 15) * 4;
        float4 xv4 = *(const float4*)(X + ((long)(b * SEQ + l0 + l)) * EMB + hh * 64 + dblk);
        Xs[dblk + 0][l] = xv4.x; Xs[dblk + 1][l] = xv4.y;
        Xs[dblk + 2][l] = xv4.z; Xs[dblk + 3][l] = xv4.w;
        float4 wv4 = *(const float4*)(W + l * 64 + dblk);     // l plays 'e' here
        Ws[dblk + 0][l] = wv4.x; Ws[dblk + 1][l] = wv4.y;
        Ws[dblk + 2][l] = wv4.z; Ws[dblk + 3][l] = wv4.w;
    }
    __syncthreads();

    const int mi = (t & 15) * 4;   // l within tile
    const int ei = (t >> 4) * 4;   // output dim
    float acc[4][4];
    #pragma unroll
    for (int i = 0; i < 4; ++i)
        #pragma unroll
        for (int j = 0; j < 4; ++j) acc[i][j] = 0.f;

    #pragma unroll 8
    for (int d = 0; d < 64; ++d) {
        float4 a = *(const float4*)&Xs[d][mi];
        float4 w = *(const float4*)&Ws[d][ei];
        const float av[4] = {a.x, a.y, a.z, a.w};
        const float wv[4] = {w.x, w.y, w.z, w.w};
        #pragma unroll
        for (int i = 0; i < 4; ++i)
            #pragma unroll
            for (int j = 0; j < 4; ++j)
                acc[i][j] = fmaf(av[i], wv[j], acc[i][j]);
    }

    const float bb[4] = {bias[ei + 0], bias[ei + 1], bias[ei + 2], bias[ei + 3]};

    // zero-multipliers for masked rows (K and V only)
    float zm[4];
    #pragma unroll
    for (int i = 0; i < 4; ++i)
        zm[i] = (mat == 0 || mask[b * SEQ + l0 + mi + i] != 0) ? 1.0f : 0.0f;

    if (mat < 2) {
        bf16_t* dh = (mat == 0) ? qh : khp;
        bf16_t* dl = (mat == 0) ? ql : klp;
        #pragma unroll
        for (int i = 0; i < 4; ++i) {
            long addr = ((long)(bh * SEQ + l0 + mi + i)) * 64 + ei;
            bf16x4 h4, l4;
            #pragma unroll
            for (int j = 0; j < 4; ++j) {
                float y = (acc[i][j] + bb[j]) * zm[i];
                bf16_t hi = (bf16_t)y;
                h4[j] = hi;
                l4[j] = (bf16_t)(y - (float)hi);
            }
            *(bf16x4*)(dh + addr) = h4;
            *(bf16x4*)(dl + addr) = l4;
        }
    } else {
        #pragma unroll
        for (int j = 0; j < 4; ++j) {
            int d = ei + j;
            bf16x4 v4;
            #pragma unroll
            for (int i = 0; i < 4; ++i) v4[i] = (bf16_t)((acc[i][j] + bb[j]) * zm[i]);
            *(bf16x4*)(vt + ((long)(bh * 64 + d)) * SEQ + l0 + mi) = v4;
        }
    }
}

// ---------------------------------------------------------------------------
// Attention.  Block = 8 waves (512 thr): 4 q-subtiles x 2 key-halves.
// Wave (qs, half) owns 64 q-rows x 1024 keys of one (b,h); 256 q-rows/block.
// Grid = 512 -> 2 blocks/CU, 16 waves/CU (4/SIMD) for latency hiding.
// Loop body identical to R5 (phase-split, K/V prefetch, no mask in loop).
// half=1 partials combined into half=0 through 67.5 KB LDS at block end.
// ---------------------------------------------------------------------------
__global__ __launch_bounds__(512, 2) void attn_kernel(
    const bf16_t* __restrict__ qh, const bf16_t* __restrict__ ql,
    const bf16_t* __restrict__ kh, const bf16_t* __restrict__ kl,
    const bf16_t* __restrict__ vt, const float* __restrict__ nmaskf,
    bf16_t* __restrict__ ao)
{
    __shared__ float lds_o[4][2][32][64];     // [qs][tile][row][dim]
    __shared__ float lds_l[4][2][64];         // [qs][tile][lane]

    // XCD swizzle: the 8 q-blocks of one bh share an XCD (K/V L2 locality)
    const int g   = blockIdx.x;
    const int xcd = g & 7;
    const int s8  = g >> 3;
    const int bh  = ((s8 >> 3) << 3) + xcd;
    const int qb  = s8 & 7;
    const int b   = bh >> 4;
    const int hh  = bh & 15;

    const int t    = threadIdx.x;
    const int lane = t & 63;
    const int wave = t >> 6;
    const int qs   = wave & 3;
    const int half = wave >> 2;
    const int col  = lane & 31;
    const int hf   = lane >> 5;

    const int q0 = qb * 256 + qs * 64;   // tile0: q0.., tile1: q0+32..

    // Q fragments (B-operand): lane holds Q[q0+col][16c + 8*hf .. +7]
    const long qoff0 = ((long)(bh * SEQ + q0 + col)) * 64 + hf * 8;
    const long qoff1 = qoff0 + 32 * 64;
    bf16x8 qfh0[4], qfl0[4], qfh1[4], qfl1[4];
    #pragma unroll
    for (int c = 0; c < 4; ++c) {
        qfh0[c] = *(const bf16x8*)(qh + qoff0 + 16 * c);
        qfl0[c] = *(const bf16x8*)(ql + qoff0 + 16 * c);
        qfh1[c] = *(const bf16x8*)(qh + qoff1 + 16 * c);
        qfl1[c] = *(const bf16x8*)(ql + qoff1 + 16 * c);
    }

    const float nmk = nmaskf[b];

    // per-lane K/V base pointers
    const bf16_t* __restrict__ pkh = kh + ((long)(bh * SEQ + col)) * 64 + hf * 8;
    const bf16_t* __restrict__ pkl = kl + ((long)(bh * SEQ + col)) * 64 + hf * 8;
    const bf16_t* __restrict__ pv0 = vt + ((long)(bh * 64 + col)) * SEQ + hf * 8;
    const bf16_t* __restrict__ pv1 = vt + ((long)(bh * 64 + 32 + col)) * SEQ + hf * 8;

    f32x16 o00 = {}, o01 = {}, o10 = {}, o11 = {};
    float l0 = 0.f, l1 = 0.f;

    const int kt0 = half * (SEQ / 2);
    const int kt1 = kt0 + (SEQ / 2);

    // prologue: K(kt0)
    bf16x8 kfh[4], kfl[4];
    #pragma unroll
    for (int c = 0; c < 4; ++c) {
        kfh[c] = *(const bf16x8*)(pkh + (long)kt0 * 64 + 16 * c);
        kfl[c] = *(const bf16x8*)(pkl + (long)kt0 * 64 + 16 * c);
    }

    #pragma unroll 1
    for (int kt = kt0; kt < kt1; kt += 32) {
        // ---- phase A: V(kt) issue + 24 QK MFMAs on K(kt) ----
        bf16x8 v00 = *(const bf16x8*)(pv0 + kt);
        bf16x8 v01 = *(const bf16x8*)(pv0 + kt + 16);
        bf16x8 v10 = *(const bf16x8*)(pv1 + kt);
        bf16x8 v11 = *(const bf16x8*)(pv1 + kt + 16);

        f32x16 s0 = {}, s1 = {};
        __builtin_amdgcn_s_setprio(1);
        #pragma unroll
        for (int c = 0; c < 4; ++c) {
            s0 = mfma32(kfh[c], qfh0[c], s0);
            s1 = mfma32(kfh[c], qfh1[c], s1);
            s0 = mfma32(kfl[c], qfh0[c], s0);
            s1 = mfma32(kfl[c], qfh1[c], s1);
            s0 = mfma32(kfh[c], qfl0[c], s0);
            s1 = mfma32(kfh[c], qfl1[c], s1);
        }
        __builtin_amdgcn_s_setprio(0);

        // ---- phase B: prefetch K(kt+32); softmax+PV both tiles ----
        // (last-iter prefetch reads past this bh's rows but stays inside
        //  the d_ws staging buffers -- values never used)
        #pragma unroll
        for (int c = 0; c < 4; ++c) {
            kfh[c] = *(const bf16x8*)(pkh + (long)(kt + 32) * 64 + 16 * c);
            kfl[c] = *(const bf16x8*)(pkl + (long)(kt + 32) * 64 + 16 * c);
        }

        // tile 0
        {
            float p[16];
            #pragma unroll
            for (int r = 0; r < 16; ++r) {
                float sv = floorf(s0[r] * 0.125f);
                p[r] = __expf(sv);
                l0 += p[r];
            }
            bf16x8 pa0, pa1;
            pack_p(p, pa0, pa1);
            __builtin_amdgcn_s_setprio(1);
            o00 = mfma32(pa0, v00, o00);
            o00 = mfma32(pa1, v01, o00);
            o01 = mfma32(pa0, v10, o01);
            o01 = mfma32(pa1, v11, o01);
            __builtin_amdgcn_s_setprio(0);
        }
        // tile 1
        {
            float p[16];
            #pragma unroll
            for (int r = 0; r < 16; ++r) {
                float sv = floorf(s1[r] * 0.125f);
                p[r] = __expf(sv);
                l1 += p[r];
            }
            bf16x8 pa0, pa1;
            pack_p(p, pa0, pa1);
            __builtin_amdgcn_s_setprio(1);
            o10 = mfma32(pa0, v00, o10);
            o10 = mfma32(pa1, v01, o10);
            o11 = mfma32(pa0, v10, o11);
            o11 = mfma32(pa1, v11, o11);
            __builtin_amdgcn_s_setprio(0);
        }
    }

    // ---- combine the two key-halves through LDS ----
    if (half == 1) {
        #pragma unroll
        for (int r = 0; r < 16; ++r) {
            int row = (r & 3) + ((r >> 2) << 3) + 4 * hf;
            lds_o[qs][0][row][col]      = o00[r];
            lds_o[qs][0][row][col + 32] = o01[r];
            lds_o[qs][1][row][col]      = o10[r];
            lds_o[qs][1][row][col + 32] = o11[r];
        }
        lds_l[qs][0][lane] = l0;
        lds_l[qs][1][lane] = l1;
    }
    __syncthreads();
    if (half == 0) {
        #pragma unroll
        for (int r = 0; r < 16; ++r) {
            int row = (r & 3) + ((r >> 2) << 3) + 4 * hf;
            o00[r] += lds_o[qs][0][row][col];
            o01[r] += lds_o[qs][0][row][col + 32];
            o10[r] += lds_o[qs][1][row][col];
            o11[r] += lds_o[qs][1][row][col + 32];
        }
        l0 += lds_l[qs][0][lane];
        l1 += lds_l[qs][1][lane];

        // epilogue, tile 0
        {
            float ltot = l0 + __shfl_xor(l0, 32) - nmk;
            float linv = 1.0f / ltot;
            const long obase = ((long)(b * SEQ + q0)) * EMB + hh * 64;
            #pragma unroll
            for (int r = 0; r < 16; ++r) {
                int row = (r & 3) + ((r >> 2) << 3) + 4 * hf;
                float li = __shfl(linv, row);
                ao[obase + (long)row * EMB + col]      = (bf16_t)(o00[r] * li);
                ao[obase + (long)row * EMB + col + 32] = (bf16_t)(o01[r] * li);
            }
        }
        // epilogue, tile 1
        {
            float ltot = l1 + __shfl_xor(l1, 32) - nmk;
            float linv = 1.0f / ltot;
            const long obase = ((long)(b * SEQ + q0 + 32)) * EMB + hh * 64;
            #pragma unroll
            for (int r = 0; r < 16; ++r) {
                int row = (r & 3) + ((r >> 2) << 3) + 4 * hf;
                float li = __shfl(linv, row);
                ao[obase + (long)row * EMB + col]      = (bf16_t)(o10[r] * li);
                ao[obase + (long)row * EMB + col + 32] = (bf16_t)(o11[r] * li);
            }
        }
    }
}

// ---------------------------------------------------------------------------
// FC: out[8192,1024] = ao_bf16 @ Wfc_bf16^T + bfc.  Block = 128x128, 4 waves,
// wave = 64x64 (2x2 32x32 MFMA tiles).  Direct global fragment loads.
// ---------------------------------------------------------------------------
__global__ __launch_bounds__(256) void fc_kernel(
    const bf16_t* __restrict__ A, const bf16_t* __restrict__ W,
    const float* __restrict__ bias, float* __restrict__ out)
{
    const int lane = threadIdx.x & 63;
    const int wave = threadIdx.x >> 6;
    const int col  = lane & 31;
    const int hf   = lane >> 5;
    const int wm   = wave & 1;
    const int wn   = wave >> 1;
    const int m0   = blockIdx.x * 128 + wm * 64;
    const int n0   = blockIdx.y * 128 + wn * 64;

    f32x16 acc[2][2] = {};
    const bf16_t* arow0 = A + (long)(m0 + col) * EMB + hf * 8;
    const bf16_t* arow1 = A + (long)(m0 + 32 + col) * EMB + hf * 8;
    const bf16_t* brow0 = W + (long)(n0 + col) * EMB + hf * 8;
    const bf16_t* brow1 = W + (long)(n0 + 32 + col) * EMB + hf * 8;

    #pragma unroll 2
    for (int k0 = 0; k0 < EMB; k0 += 16) {
        bf16x8 a0 = *(const bf16x8*)(arow0 + k0);
        bf16x8 a1 = *(const bf16x8*)(arow1 + k0);
        bf16x8 b0 = *(const bf16x8*)(brow0 + k0);
        bf16x8 b1 = *(const bf16x8*)(brow1 + k0);
        acc[0][0] = mfma32(a0, b0, acc[0][0]);
        acc[0][1] = mfma32(a0, b1, acc[0][1]);
        acc[1][0] = mfma32(a1, b0, acc[1][0]);
        acc[1][1] = mfma32(a1, b1, acc[1][1]);
    }

    const float b0v = bias[n0 + col];
    const float b1v = bias[n0 + 32 + col];
    #pragma unroll
    for (int mt = 0; mt < 2; ++mt) {
        #pragma unroll
        for (int r = 0; r < 16; ++r) {
            int mrow = m0 + mt * 32 + (r & 3) + ((r >> 2) << 3) + 4 * hf;
            out[(long)mrow * EMB + n0 + col]      = acc[mt][0][r] + b0v;
            out[(long)mrow * EMB + n0 + 32 + col] = acc[mt][1][r] + b1v;
        }
    }
}

// ---------------------------------------------------------------------------
extern "C" void kernel_launch(void* const* d_in, const int* in_sizes, int n_in,
                              void* d_out, int out_size, void* d_ws, size_t ws_size,
                              hipStream_t stream)
{
    const float* q    = (const float*)d_in[0];
    const float* k    = (const float*)d_in[1];
    const float* v    = (const float*)d_in[2];
    const int*   mask = (const int*)  d_in[3];
    const float* Wq   = (const float*)d_in[4];
    const float* bq   = (const float*)d_in[5];
    const float* Wk   = (const float*)d_in[6];
    const float* bk   = (const float*)d_in[7];
    const float* Wv   = (const float*)d_in[8];
    const float* bv   = (const float*)d_in[9];
    const float* Wfc  = (const float*)d_in[10];
    const float* bfc  = (const float*)d_in[11];
    float* out = (float*)d_out;

    const long NP = (long)BATCH * HEADS * SEQ * 64;   // 8,388,608 elems
    bf16_t* qhp = (bf16_t*)d_ws;
    bf16_t* qlp = qhp + NP;
    bf16_t* khp = qlp + NP;
    bf16_t* klp = khp + NP;
    bf16_t* vtp = klp + NP;
    bf16_t* aop = vtp + NP;                        // [B*SEQ][EMB] bf16
    bf16_t* wbp = aop + (long)BATCH * SEQ * EMB;   // [EMB][EMB] bf16
    float*  nmf = (float*)(wbp + (long)EMB * EMB); // [BATCH] floats

    nmask_kernel<<<BATCH, 256, 0, stream>>>(mask, nmf);
    wconv_kernel<<<(EMB * EMB / 4) / 256, 256, 0, stream>>>(Wfc, wbp, EMB * EMB);

    dim3 gP(2048, 3);
    proj_kernel<<<gP, 256, 0, stream>>>(q, k, v, Wq, bq, Wk, bk, Wv, bv, mask,
                                        qhp, qlp, khp, klp, vtp);

    attn_kernel<<<512, 512, 0, stream>>>(qhp, qlp, khp, klp, vtp, nmf, aop);

    dim3 gC(64, 8);
    fc_kernel<<<gC, 256, 0, stream>>>(aop, wbp, bfc, out);
}

// Round 9
// 223.392 us; speedup vs baseline: 1.4036x; 1.4036x over previous
//
#include <hip/hip_runtime.h>
#include <math.h>

#define HEADS 16
#define EMB 1024
#define BATCH 4
#define SEQ 2048

#define TILE_B 12288L          // 12KB per 32-key K/V fragment tile
#define BH_B   (64L * TILE_B)  // 768KB per (b,h):  64 tiles
#define MT_B   65536L          // 64KB per 32-row A/W fragment tile (64 frags x 1KB)

typedef __bf16 bf16_t;
typedef __bf16 bf16x4 __attribute__((ext_vector_type(4)));
typedef __bf16 bf16x8 __attribute__((ext_vector_type(8)));
typedef float f32x4 __attribute__((ext_vector_type(4)));
typedef float f32x16 __attribute__((ext_vector_type(16)));
typedef unsigned int u32x4 __attribute__((ext_vector_type(4)));

__device__ __forceinline__ f32x16 mfma32(bf16x8 a, bf16x8 b, f32x16 c) {
    return __builtin_amdgcn_mfma_f32_32x32x16_bf16(a, b, c, 0, 0, 0);
}

__device__ __forceinline__ unsigned cvtpk(float lo, float hi) {
    unsigned r;
    asm("v_cvt_pk_bf16_f32 %0, %1, %2" : "=v"(r) : "v"(lo), "v"(hi));
    return r;
}

__device__ __forceinline__ void plswap(unsigned &a, unsigned &b) {
    asm volatile("v_permlane32_swap_b32 %0, %1" : "+v"(a), "+v"(b));
}

__device__ __forceinline__ unsigned short bfbits(float x) {
    return __builtin_bit_cast(unsigned short, (bf16_t)x);
}

// Pack 16 per-lane P values (QK^T output layout) into the two PV A-fragments.
__device__ __forceinline__ void pack_p(const float* p, bf16x8& pa0, bf16x8& pa1) {
    unsigned w0 = cvtpk(p[0], p[1]),   w1 = cvtpk(p[2], p[3]);
    unsigned w2 = cvtpk(p[4], p[5]),   w3 = cvtpk(p[6], p[7]);
    plswap(w0, w2); plswap(w1, w3);
    unsigned w4 = cvtpk(p[8], p[9]),   w5 = cvtpk(p[10], p[11]);
    unsigned w6 = cvtpk(p[12], p[13]), w7 = cvtpk(p[14], p[15]);
    plswap(w4, w6); plswap(w5, w7);
    u32x4 ua = {w0, w1, w2, w3};
    u32x4 ub = {w4, w5, w6, w7};
    pa0 = __builtin_bit_cast(bf16x8, ua);
    pa1 = __builtin_bit_cast(bf16x8, ub);
}

// ---------------------------------------------------------------------------
// Per-batch masked-key count (as float).
// ---------------------------------------------------------------------------
__global__ void nmask_kernel(const int* __restrict__ mask, float* __restrict__ nmaskf) {
    const int b = blockIdx.x;
    const int t = threadIdx.x;
    int cnt = 0;
    #pragma unroll
    for (int i = 0; i < SEQ / 256; ++i)
        cnt += (mask[b * SEQ + t + i * 256] == 0);
    #pragma unroll
    for (int d = 1; d < 64; d <<= 1) cnt += __shfl_xor(cnt, d);
    __shared__ int red[4];
    if ((t & 63) == 0) red[t >> 6] = cnt;
    __syncthreads();
    if (t == 0) nmaskf[b] = (float)(red[0] + red[1] + red[2] + red[3]);
}

// Wfc f32 -> bf16 fragment layout: element (n,k) ->
//   wf[(n>>5)*MT_B + (k>>4)*1024 + ((n&31)+32*((k>>3)&1))*16 + (k&7)*2]
__global__ void wconv_kernel(const float* __restrict__ w, char* __restrict__ wf, int n_elems) {
    int i = (blockIdx.x * 256 + threadIdx.x) * 4;
    if (i < n_elems) {
        int n = i >> 10, k = i & 1023;
        float4 f = *(const float4*)(w + i);
        bf16x4 o;
        o[0] = (bf16_t)f.x; o[1] = (bf16_t)f.y; o[2] = (bf16_t)f.z; o[3] = (bf16_t)f.w;
        long byt = (long)(n >> 5) * MT_B + (long)(k >> 4) * 1024
                 + (long)((n & 31) + 32 * ((k >> 3) & 1)) * 16 + (k & 7) * 2;
        *(bf16x4*)(wf + byt) = o;
    }
}

// ---------------------------------------------------------------------------
// Projections.  q_hi/q_lo stay row-major [bh][l][64].  K (hi+lo) and V are
// written in MFMA-FRAGMENT layout: per (bh, 32-key tile) a 12KB block:
//   [0KB)  kh frag c=0..3   : byte c*1024 + lane*16 + j*2 = K[col][16c+8hf+j]
//   [4KB)  kl frag c=0..3
//   [8KB)  v  frag idx=dh*2+c' : V[16c'+8hf+j][32dh+col]
// so attention's loads are lane*16-coalesced.  Masked keys zeroed (p=1,
// V=0; denominator corrected by nmask).
// ---------------------------------------------------------------------------
__global__ __launch_bounds__(256) void proj_kernel(
    const float* __restrict__ xq, const float* __restrict__ xk, const float* __restrict__ xv,
    const float* __restrict__ Wq, const float* __restrict__ bq,
    const float* __restrict__ Wk, const float* __restrict__ bk,
    const float* __restrict__ Wv, const float* __restrict__ bv,
    const int* __restrict__ mask,
    bf16_t* __restrict__ qh, bf16_t* __restrict__ ql,
    char* __restrict__ kvf)
{
    __shared__ float Xs[64][68];   // Xs[d][l]
    __shared__ float Ws[64][68];   // Ws[d][e]

    const int t   = threadIdx.x;
    const int mat = blockIdx.y;
    const int bh  = blockIdx.x >> 5;
    const int l0  = (blockIdx.x & 31) * 64;
    const int b   = bh >> 4;
    const int hh  = bh & 15;

    const float* __restrict__ X    = (mat == 0) ? xq : (mat == 1) ? xk : xv;
    const float* __restrict__ W    = (mat == 0) ? Wq : (mat == 1) ? Wk : Wv;
    const float* __restrict__ bias = (mat == 0) ? bq : (mat == 1) ? bk : bv;

    #pragma unroll
    for (int i = 0; i < 4; ++i) {
        int c    = t + i * 256;
        int l    = c >> 4;
        int dblk = (c & 15) * 4;
        float4 xv4 = *(const float4*)(X + ((long)(b * SEQ + l0 + l)) * EMB + hh * 64 + dblk);
        Xs[dblk + 0][l] = xv4.x; Xs[dblk + 1][l] = xv4.y;
        Xs[dblk + 2][l] = xv4.z; Xs[dblk + 3][l] = xv4.w;
        float4 wv4 = *(const float4*)(W + l * 64 + dblk);
        Ws[dblk + 0][l] = wv4.x; Ws[dblk + 1][l] = wv4.y;
        Ws[dblk + 2][l] = wv4.z; Ws[dblk + 3][l] = wv4.w;
    }
    __syncthreads();

    const int mi = (t & 15) * 4;   // l within tile
    const int ei = (t >> 4) * 4;   // output dim
    float acc[4][4];
    #pragma unroll
    for (int i = 0; i < 4; ++i)
        #pragma unroll
        for (int j = 0; j < 4; ++j) acc[i][j] = 0.f;

    #pragma unroll 8
    for (int d = 0; d < 64; ++d) {
        float4 a = *(const float4*)&Xs[d][mi];
        float4 w = *(const float4*)&Ws[d][ei];
        const float av[4] = {a.x, a.y, a.z, a.w};
        const float wv[4] = {w.x, w.y, w.z, w.w};
        #pragma unroll
        for (int i = 0; i < 4; ++i)
            #pragma unroll
            for (int j = 0; j < 4; ++j)
                acc[i][j] = fmaf(av[i], wv[j], acc[i][j]);
    }

    const float bb[4] = {bias[ei + 0], bias[ei + 1], bias[ei + 2], bias[ei + 3]};

    // zero-multipliers for masked rows (K and V only)
    float zm[4];
    #pragma unroll
    for (int i = 0; i < 4; ++i)
        zm[i] = (mat == 0 || mask[b * SEQ + l0 + mi + i] != 0) ? 1.0f : 0.0f;

    if (mat == 0) {
        #pragma unroll
        for (int i = 0; i < 4; ++i) {
            long addr = ((long)(bh * SEQ + l0 + mi + i)) * 64 + ei;
            bf16x4 h4, l4;
            #pragma unroll
            for (int j = 0; j < 4; ++j) {
                float y = acc[i][j] + bb[j];
                bf16_t hi = (bf16_t)y;
                h4[j] = hi;
                l4[j] = (bf16_t)(y - (float)hi);
            }
            *(bf16x4*)(qh + addr) = h4;
            *(bf16x4*)(ql + addr) = l4;
        }
    } else if (mat == 1) {
        char* kvb = kvf + (long)bh * BH_B;
        #pragma unroll
        for (int i = 0; i < 4; ++i) {
            int l = l0 + mi + i;
            bf16x4 h4, l4;
            #pragma unroll
            for (int j = 0; j < 4; ++j) {
                float y = (acc[i][j] + bb[j]) * zm[i];
                bf16_t hi = (bf16_t)y;
                h4[j] = hi;
                l4[j] = (bf16_t)(y - (float)hi);
            }
            long byt = (long)(l >> 5) * TILE_B + (long)(ei >> 4) * 1024
                     + (long)((l & 31) + 32 * ((ei >> 3) & 1)) * 16 + (ei & 7) * 2;
            *(bf16x4*)(kvb + byt) = h4;
            *(bf16x4*)(kvb + byt + 4096) = l4;
        }
    } else {
        char* kvb = kvf + (long)bh * BH_B;
        #pragma unroll
        for (int i = 0; i < 4; ++i) {
            int l = l0 + mi + i;               // key index
            long tb = (long)(l >> 5) * TILE_B + 8192 + (l & 7) * 2;
            int c2  = (l & 31) >> 4;
            int hfk = (l >> 3) & 1;
            #pragma unroll
            for (int jj = 0; jj < 4; ++jj) {
                int d = ei + jj;
                float val = (acc[i][jj] + bb[jj]) * zm[i];
                long byt = tb + (long)(((d >> 5) << 1) + c2) * 1024
                         + (long)((d & 31) + 32 * hfk) * 16;
                *(unsigned short*)(kvb + byt) = bfbits(val);
            }
        }
    }
}

// ---------------------------------------------------------------------------
// Attention.  Block = 4 independent waves; wave owns 64 q-rows (2 tiles of
// 32) of one (b,h) over all 2048 keys.  Grid = 512.
// All K/V loads are COALESCED 1KB fragment bursts from kvf (base + lane*16).
// Phase-split loop (QK cluster, then softmax+PV; K(kt+32) prefetched).
// Output written directly in FC A-fragment layout (af).
// ---------------------------------------------------------------------------
__global__ __launch_bounds__(256, 2) void attn_kernel(
    const bf16_t* __restrict__ qh, const bf16_t* __restrict__ ql,
    const char* __restrict__ kvf, const float* __restrict__ nmaskf,
    char* __restrict__ af)
{
    // XCD swizzle: the 8 q-blocks of one bh share an XCD (K/V L2 locality)
    const int g   = blockIdx.x;
    const int xcd = g & 7;
    const int s8  = g >> 3;
    const int bh  = ((s8 >> 3) << 3) + xcd;
    const int qb  = s8 & 7;
    const int b   = bh >> 4;
    const int hh  = bh & 15;

    const int lane = threadIdx.x & 63;
    const int wave = threadIdx.x >> 6;
    const int col  = lane & 31;
    const int hf   = lane >> 5;

    const int q0 = qb * 256 + wave * 64;   // tile0: q0.., tile1: q0+32..

    // Q fragments (B-operand): lane holds Q[q0+col][16c + 8*hf .. +7]
    const long qoff0 = ((long)(bh * SEQ + q0 + col)) * 64 + hf * 8;
    const long qoff1 = qoff0 + 32 * 64;
    bf16x8 qfh0[4], qfl0[4], qfh1[4], qfl1[4];
    #pragma unroll
    for (int c = 0; c < 4; ++c) {
        qfh0[c] = *(const bf16x8*)(qh + qoff0 + 16 * c);
        qfl0[c] = *(const bf16x8*)(ql + qoff0 + 16 * c);
        qfh1[c] = *(const bf16x8*)(qh + qoff1 + 16 * c);
        qfl1[c] = *(const bf16x8*)(ql + qoff1 + 16 * c);
    }

    const float nmk = nmaskf[b];

    // coalesced fragment base: all lanes stride 16B
    const char* __restrict__ kvb = kvf + (long)bh * BH_B + (long)lane * 16;

    f32x16 o00 = {}, o01 = {}, o10 = {}, o11 = {};
    float l0 = 0.f, l1 = 0.f;

    // prologue: K tile 0
    bf16x8 kfh[4], kfl[4];
    #pragma unroll
    for (int c = 0; c < 4; ++c) {
        kfh[c] = *(const bf16x8*)(kvb + c * 1024);
        kfl[c] = *(const bf16x8*)(kvb + 4096 + c * 1024);
    }

    #pragma unroll 1
    for (int kt = 0; kt < SEQ; kt += 32) {
        const long toff = (long)(kt >> 5) * TILE_B;
        // ---- phase A: V(kt) issue + 24 QK MFMAs on K(kt) ----
        bf16x8 v00 = *(const bf16x8*)(kvb + toff + 8192);
        bf16x8 v01 = *(const bf16x8*)(kvb + toff + 9216);
        bf16x8 v10 = *(const bf16x8*)(kvb + toff + 10240);
        bf16x8 v11 = *(const bf16x8*)(kvb + toff + 11264);

        f32x16 s0 = {}, s1 = {};
        __builtin_amdgcn_s_setprio(1);
        #pragma unroll
        for (int c = 0; c < 4; ++c) {
            s0 = mfma32(kfh[c], qfh0[c], s0);
            s1 = mfma32(kfh[c], qfh1[c], s1);
            s0 = mfma32(kfl[c], qfh0[c], s0);
            s1 = mfma32(kfl[c], qfh1[c], s1);
            s0 = mfma32(kfh[c], qfl0[c], s0);
            s1 = mfma32(kfh[c], qfl1[c], s1);
        }
        __builtin_amdgcn_s_setprio(0);

        // ---- phase B: prefetch K(kt+32); softmax+PV both tiles ----
        // (last-iter prefetch reads the next bh's tile 0 / start of af --
        //  in-bounds of d_ws, values never used)
        #pragma unroll
        for (int c = 0; c < 4; ++c) {
            kfh[c] = *(const bf16x8*)(kvb + toff + TILE_B + c * 1024);
            kfl[c] = *(const bf16x8*)(kvb + toff + TILE_B + 4096 + c * 1024);
        }

        // tile 0
        {
            float p[16];
            #pragma unroll
            for (int r = 0; r < 16; ++r) {
                float sv = floorf(s0[r] * 0.125f);
                p[r] = __expf(sv);
                l0 += p[r];
            }
            bf16x8 pa0, pa1;
            pack_p(p, pa0, pa1);
            __builtin_amdgcn_s_setprio(1);
            o00 = mfma32(pa0, v00, o00);
            o00 = mfma32(pa1, v01, o00);
            o01 = mfma32(pa0, v10, o01);
            o01 = mfma32(pa1, v11, o01);
            __builtin_amdgcn_s_setprio(0);
        }
        // tile 1
        {
            float p[16];
            #pragma unroll
            for (int r = 0; r < 16; ++r) {
                float sv = floorf(s1[r] * 0.125f);
                p[r] = __expf(sv);
                l1 += p[r];
            }
            bf16x8 pa0, pa1;
            pack_p(p, pa0, pa1);
            __builtin_amdgcn_s_setprio(1);
            o10 = mfma32(pa0, v00, o10);
            o10 = mfma32(pa1, v01, o10);
            o11 = mfma32(pa0, v10, o11);
            o11 = mfma32(pa1, v11, o11);
            __builtin_amdgcn_s_setprio(0);
        }
    }

    // ---- epilogue: write into FC A-fragment layout ----
    // element (m = b*SEQ + q, k = hh*64 + dcol):
    //   af[(m>>5)*MT_B + (k>>4)*1024 + ((m&31)+32*((k>>3)&1))*16 + (k&7)*2]
    const long mtb = ((long)(b * SEQ + q0) >> 5) * MT_B;
    const int  hfo = (col >> 3) & 1;
    const int  job = (col & 7) * 2;
    const int  cf0 = hh * 4 + (col >> 4);        // dims col
    const int  cf1 = cf0 + 2;                    // dims col+32
    // tile 0
    {
        float ltot = l0 + __shfl_xor(l0, 32) - nmk;
        float linv = 1.0f / ltot;
        #pragma unroll
        for (int r = 0; r < 16; ++r) {
            int row = (r & 3) + ((r >> 2) << 3) + 4 * hf;
            float li = __shfl(linv, row);
            long lb = mtb + (long)(row + 32 * hfo) * 16 + job;
            *(unsigned short*)(af + lb + (long)cf0 * 1024) = bfbits(o00[r] * li);
            *(unsigned short*)(af + lb + (long)cf1 * 1024) = bfbits(o01[r] * li);
        }
    }
    // tile 1
    {
        float ltot = l1 + __shfl_xor(l1, 32) - nmk;
        float linv = 1.0f / ltot;
        #pragma unroll
        for (int r = 0; r < 16; ++r) {
            int row = (r & 3) + ((r >> 2) << 3) + 4 * hf;
            float li = __shfl(linv, row);
            long lb = mtb + MT_B + (long)(row + 32 * hfo) * 16 + job;
            *(unsigned short*)(af + lb + (long)cf0 * 1024) = bfbits(o10[r] * li);
            *(unsigned short*)(af + lb + (long)cf1 * 1024) = bfbits(o11[r] * li);
        }
    }
}

// ---------------------------------------------------------------------------
// FC: out[8192,1024] = A @ W^T + bfc with A, W in fragment layout (af, wf).
// Block = 128x128, 4 waves, wave = 64x64 (2x2 32x32 MFMA tiles).
// All loads are coalesced lane*16 fragment bursts.
// ---------------------------------------------------------------------------
__global__ __launch_bounds__(256) void fc_kernel(
    const char* __restrict__ af, const char* __restrict__ wf,
    const float* __restrict__ bias, float* __restrict__ out)
{
    const int lane = threadIdx.x & 63;
    const int wave = threadIdx.x >> 6;
    const int col  = lane & 31;
    const int hf   = lane >> 5;
    const int wm   = wave & 1;
    const int wn   = wave >> 1;
    const int m0   = blockIdx.x * 128 + wm * 64;
    const int n0   = blockIdx.y * 128 + wn * 64;

    f32x16 acc[2][2] = {};
    const char* afb = af + (long)(m0 >> 5) * MT_B + (long)lane * 16;
    const char* wfb = wf + (long)(n0 >> 5) * MT_B + (long)lane * 16;

    #pragma unroll 2
    for (int k0 = 0; k0 < EMB; k0 += 16) {
        const long ko = (long)(k0 >> 4) * 1024;
        bf16x8 a0 = *(const bf16x8*)(afb + ko);
        bf16x8 a1 = *(const bf16x8*)(afb + MT_B + ko);
        bf16x8 b0 = *(const bf16x8*)(wfb + ko);
        bf16x8 b1 = *(const bf16x8*)(wfb + MT_B + ko);
        acc[0][0] = mfma32(a0, b0, acc[0][0]);
        acc[0][1] = mfma32(a0, b1, acc[0][1]);
        acc[1][0] = mfma32(a1, b0, acc[1][0]);
        acc[1][1] = mfma32(a1, b1, acc[1][1]);
    }

    const float b0v = bias[n0 + col];
    const float b1v = bias[n0 + 32 + col];
    #pragma unroll
    for (int mt = 0; mt < 2; ++mt) {
        #pragma unroll
        for (int r = 0; r < 16; ++r) {
            int mrow = m0 + mt * 32 + (r & 3) + ((r >> 2) << 3) + 4 * hf;
            out[(long)mrow * EMB + n0 + col]      = acc[mt][0][r] + b0v;
            out[(long)mrow * EMB + n0 + 32 + col] = acc[mt][1][r] + b1v;
        }
    }
}

// ---------------------------------------------------------------------------
extern "C" void kernel_launch(void* const* d_in, const int* in_sizes, int n_in,
                              void* d_out, int out_size, void* d_ws, size_t ws_size,
                              hipStream_t stream)
{
    const float* q    = (const float*)d_in[0];
    const float* k    = (const float*)d_in[1];
    const float* v    = (const float*)d_in[2];
    const int*   mask = (const int*)  d_in[3];
    const float* Wq   = (const float*)d_in[4];
    const float* bq   = (const float*)d_in[5];
    const float* Wk   = (const float*)d_in[6];
    const float* bk   = (const float*)d_in[7];
    const float* Wv   = (const float*)d_in[8];
    const float* bv   = (const float*)d_in[9];
    const float* Wfc  = (const float*)d_in[10];
    const float* bfc  = (const float*)d_in[11];
    float* out = (float*)d_out;

    const long NP = (long)BATCH * HEADS * SEQ * 64;   // 8,388,608 elems
    bf16_t* qhp = (bf16_t*)d_ws;                      // 16MB
    bf16_t* qlp = qhp + NP;                           // 16MB
    char*   kvf = (char*)(qlp + NP);                  // 48MB K/V fragments
    char*   afp = kvf + 64L * BH_B;                   // 16MB A fragments
    char*   wfp = afp + (long)(BATCH * SEQ / 32) * MT_B;  // 2MB W fragments
    float*  nmf = (float*)(wfp + (long)(EMB / 32) * MT_B);

    nmask_kernel<<<BATCH, 256, 0, stream>>>(mask, nmf);
    wconv_kernel<<<(EMB * EMB / 4) / 256, 256, 0, stream>>>(Wfc, wfp, EMB * EMB);

    dim3 gP(2048, 3);
    proj_kernel<<<gP, 256, 0, stream>>>(q, k, v, Wq, bq, Wk, bk, Wv, bv, mask,
                                        qhp, qlp, kvf);

    attn_kernel<<<512, 256, 0, stream>>>(qhp, qlp, kvf, nmf, afp);

    dim3 gC(64, 8);
    fc_kernel<<<gC, 256, 0, stream>>>(afp, wfp, bfc, out);
}

// Round 10
// 213.169 us; speedup vs baseline: 1.4709x; 1.0480x over previous
//
#include <hip/hip_runtime.h>
#include <math.h>

#define HEADS 16
#define EMB 1024
#define BATCH 4
#define SEQ 2048

#define TILE_B 12288L          // 12KB per 32-key K/V fragment tile
#define BH_B   (64L * TILE_B)  // 768KB per (b,h):  64 tiles
#define MT_B   65536L          // 64KB per 32-row A/W fragment tile (64 frags x 1KB)

typedef __bf16 bf16_t;
typedef __bf16 bf16x4 __attribute__((ext_vector_type(4)));
typedef __bf16 bf16x8 __attribute__((ext_vector_type(8)));
typedef float f32x4 __attribute__((ext_vector_type(4)));
typedef float f32x16 __attribute__((ext_vector_type(16)));
typedef unsigned int u32x4 __attribute__((ext_vector_type(4)));

__device__ __forceinline__ f32x16 mfma32(bf16x8 a, bf16x8 b, f32x16 c) {
    return __builtin_amdgcn_mfma_f32_32x32x16_bf16(a, b, c, 0, 0, 0);
}

__device__ __forceinline__ unsigned cvtpk(float lo, float hi) {
    unsigned r;
    asm("v_cvt_pk_bf16_f32 %0, %1, %2" : "=v"(r) : "v"(lo), "v"(hi));
    return r;
}

__device__ __forceinline__ void plswap(unsigned &a, unsigned &b) {
    asm volatile("v_permlane32_swap_b32 %0, %1" : "+v"(a), "+v"(b));
}

__device__ __forceinline__ unsigned short bfbits(float x) {
    return __builtin_bit_cast(unsigned short, (bf16_t)x);
}

// async global->LDS, 16B/lane.  dest = wave-uniform base + lane*16.
__device__ __forceinline__ void gload_lds16(const void* g, void* l) {
    __builtin_amdgcn_global_load_lds(
        (const __attribute__((address_space(1))) void*)g,
        (__attribute__((address_space(3))) void*)l,
        16, 0, 0);
}

// Pack 16 per-lane P values (QK^T output layout) into the two PV A-fragments.
__device__ __forceinline__ void pack_p(const float* p, bf16x8& pa0, bf16x8& pa1) {
    unsigned w0 = cvtpk(p[0], p[1]),   w1 = cvtpk(p[2], p[3]);
    unsigned w2 = cvtpk(p[4], p[5]),   w3 = cvtpk(p[6], p[7]);
    plswap(w0, w2); plswap(w1, w3);
    unsigned w4 = cvtpk(p[8], p[9]),   w5 = cvtpk(p[10], p[11]);
    unsigned w6 = cvtpk(p[12], p[13]), w7 = cvtpk(p[14], p[15]);
    plswap(w4, w6); plswap(w5, w7);
    u32x4 ua = {w0, w1, w2, w3};
    u32x4 ub = {w4, w5, w6, w7};
    pa0 = __builtin_bit_cast(bf16x8, ua);
    pa1 = __builtin_bit_cast(bf16x8, ub);
}

// ---------------------------------------------------------------------------
// Per-batch masked-key count (as float).
// ---------------------------------------------------------------------------
__global__ void nmask_kernel(const int* __restrict__ mask, float* __restrict__ nmaskf) {
    const int b = blockIdx.x;
    const int t = threadIdx.x;
    int cnt = 0;
    #pragma unroll
    for (int i = 0; i < SEQ / 256; ++i)
        cnt += (mask[b * SEQ + t + i * 256] == 0);
    #pragma unroll
    for (int d = 1; d < 64; d <<= 1) cnt += __shfl_xor(cnt, d);
    __shared__ int red[4];
    if ((t & 63) == 0) red[t >> 6] = cnt;
    __syncthreads();
    if (t == 0) nmaskf[b] = (float)(red[0] + red[1] + red[2] + red[3]);
}

// Wfc f32 -> bf16 fragment layout: element (n,k) ->
//   wf[(n>>5)*MT_B + (k>>4)*1024 + ((n&31)+32*((k>>3)&1))*16 + (k&7)*2]
__global__ void wconv_kernel(const float* __restrict__ w, char* __restrict__ wf, int n_elems) {
    int i = (blockIdx.x * 256 + threadIdx.x) * 4;
    if (i < n_elems) {
        int n = i >> 10, k = i & 1023;
        float4 f = *(const float4*)(w + i);
        bf16x4 o;
        o[0] = (bf16_t)f.x; o[1] = (bf16_t)f.y; o[2] = (bf16_t)f.z; o[3] = (bf16_t)f.w;
        long byt = (long)(n >> 5) * MT_B + (long)(k >> 4) * 1024
                 + (long)((n & 31) + 32 * ((k >> 3) & 1)) * 16 + (k & 7) * 2;
        *(bf16x4*)(wf + byt) = o;
    }
}

// ---------------------------------------------------------------------------
// Projections.  q_hi/q_lo row-major [bh][l][64].  K (hi+lo, PRE-SCALED by
// 1/8) and V in MFMA-fragment layout (12KB per 32-key tile).  Masked keys
// zeroed (p=1, V=0; denominator corrected by nmask).
// ---------------------------------------------------------------------------
__global__ __launch_bounds__(256) void proj_kernel(
    const float* __restrict__ xq, const float* __restrict__ xk, const float* __restrict__ xv,
    const float* __restrict__ Wq, const float* __restrict__ bq,
    const float* __restrict__ Wk, const float* __restrict__ bk,
    const float* __restrict__ Wv, const float* __restrict__ bv,
    const int* __restrict__ mask,
    bf16_t* __restrict__ qh, bf16_t* __restrict__ ql,
    char* __restrict__ kvf)
{
    __shared__ float Xs[64][68];   // Xs[d][l]
    __shared__ float Ws[64][68];   // Ws[d][e]

    const int t   = threadIdx.x;
    const int mat = blockIdx.y;
    const int bh  = blockIdx.x >> 5;
    const int l0  = (blockIdx.x & 31) * 64;
    const int b   = bh >> 4;
    const int hh  = bh & 15;

    const float* __restrict__ X    = (mat == 0) ? xq : (mat == 1) ? xk : xv;
    const float* __restrict__ W    = (mat == 0) ? Wq : (mat == 1) ? Wk : Wv;
    const float* __restrict__ bias = (mat == 0) ? bq : (mat == 1) ? bk : bv;

    #pragma unroll
    for (int i = 0; i < 4; ++i) {
        int c    = t + i * 256;
        int l    = c >> 4;
        int dblk = (c & 15) * 4;
        float4 xv4 = *(const float4*)(X + ((long)(b * SEQ + l0 + l)) * EMB + hh * 64 + dblk);
        Xs[dblk + 0][l] = xv4.x; Xs[dblk + 1][l] = xv4.y;
        Xs[dblk + 2][l] = xv4.z; Xs[dblk + 3][l] = xv4.w;
        float4 wv4 = *(const float4*)(W + l * 64 + dblk);
        Ws[dblk + 0][l] = wv4.x; Ws[dblk + 1][l] = wv4.y;
        Ws[dblk + 2][l] = wv4.z; Ws[dblk + 3][l] = wv4.w;
    }
    __syncthreads();

    const int mi = (t & 15) * 4;   // l within tile
    const int ei = (t >> 4) * 4;   // output dim
    float acc[4][4];
    #pragma unroll
    for (int i = 0; i < 4; ++i)
        #pragma unroll
        for (int j = 0; j < 4; ++j) acc[i][j] = 0.f;

    #pragma unroll 8
    for (int d = 0; d < 64; ++d) {
        float4 a = *(const float4*)&Xs[d][mi];
        float4 w = *(const float4*)&Ws[d][ei];
        const float av[4] = {a.x, a.y, a.z, a.w};
        const float wv[4] = {w.x, w.y, w.z, w.w};
        #pragma unroll
        for (int i = 0; i < 4; ++i)
            #pragma unroll
            for (int j = 0; j < 4; ++j)
                acc[i][j] = fmaf(av[i], wv[j], acc[i][j]);
    }

    const float bb[4] = {bias[ei + 0], bias[ei + 1], bias[ei + 2], bias[ei + 3]};

    // zero-multipliers for masked rows (K and V only)
    float zm[4];
    #pragma unroll
    for (int i = 0; i < 4; ++i)
        zm[i] = (mat == 0 || mask[b * SEQ + l0 + mi + i] != 0) ? 1.0f : 0.0f;

    if (mat == 0) {
        #pragma unroll
        for (int i = 0; i < 4; ++i) {
            long addr = ((long)(bh * SEQ + l0 + mi + i)) * 64 + ei;
            bf16x4 h4, l4;
            #pragma unroll
            for (int j = 0; j < 4; ++j) {
                float y = acc[i][j] + bb[j];
                bf16_t hi = (bf16_t)y;
                h4[j] = hi;
                l4[j] = (bf16_t)(y - (float)hi);
            }
            *(bf16x4*)(qh + addr) = h4;
            *(bf16x4*)(ql + addr) = l4;
        }
    } else if (mat == 1) {
        char* kvb = kvf + (long)bh * BH_B;
        #pragma unroll
        for (int i = 0; i < 4; ++i) {
            int l = l0 + mi + i;
            bf16x4 h4, l4;
            #pragma unroll
            for (int j = 0; j < 4; ++j) {
                float y = (acc[i][j] + bb[j]) * zm[i] * 0.125f;   // pre-scale 1/8
                bf16_t hi = (bf16_t)y;
                h4[j] = hi;
                l4[j] = (bf16_t)(y - (float)hi);
            }
            long byt = (long)(l >> 5) * TILE_B + (long)(ei >> 4) * 1024
                     + (long)((l & 31) + 32 * ((ei >> 3) & 1)) * 16 + (ei & 7) * 2;
            *(bf16x4*)(kvb + byt) = h4;
            *(bf16x4*)(kvb + byt + 4096) = l4;
        }
    } else {
        char* kvb = kvf + (long)bh * BH_B;
        #pragma unroll
        for (int i = 0; i < 4; ++i) {
            int l = l0 + mi + i;               // key index
            long tb = (long)(l >> 5) * TILE_B + 8192 + (l & 7) * 2;
            int c2  = (l & 31) >> 4;
            int hfk = (l >> 3) & 1;
            #pragma unroll
            for (int jj = 0; jj < 4; ++jj) {
                int d = ei + jj;
                float val = (acc[i][jj] + bb[jj]) * zm[i];
                long byt = tb + (long)(((d >> 5) << 1) + c2) * 1024
                         + (long)((d & 31) + 32 * hfk) * 16;
                *(unsigned short*)(kvb + byt) = bfbits(val);
            }
        }
    }
}

// ---------------------------------------------------------------------------
// Attention.  Block = 4 waves, each 64 q-rows of one (b,h); grid = 512.
// K/V fragment tiles STAGED ONCE per block into double-buffered LDS via
// global_load_lds (12KB/tile; 3 instrs/wave), deduping the 4x redundant
// per-wave loads.  ds_read_b128 fragment reads (2-way bank alias = free).
// K pre-scaled by 1/8 -> sv = floor(s) directly.
// Output written directly in FC A-fragment layout (af).
// ---------------------------------------------------------------------------
__global__ __launch_bounds__(256, 2) void attn_kernel(
    const bf16_t* __restrict__ qh, const bf16_t* __restrict__ ql,
    const char* __restrict__ kvf, const float* __restrict__ nmaskf,
    char* __restrict__ af)
{
    __shared__ __align__(16) char kvt[2][12288];

    // XCD swizzle: the 8 q-blocks of one bh share an XCD (K/V L2 locality)
    const int g   = blockIdx.x;
    const int xcd = g & 7;
    const int s8  = g >> 3;
    const int bh  = ((s8 >> 3) << 3) + xcd;
    const int qb  = s8 & 7;
    const int b   = bh >> 4;
    const int hh  = bh & 15;

    const int lane = threadIdx.x & 63;
    const int wave = threadIdx.x >> 6;
    const int col  = lane & 31;
    const int hf   = lane >> 5;

    const int q0 = qb * 256 + wave * 64;   // tile0: q0.., tile1: q0+32..

    // Q fragments (B-operand): lane holds Q[q0+col][16c + 8*hf .. +7]
    const long qoff0 = ((long)(bh * SEQ + q0 + col)) * 64 + hf * 8;
    const long qoff1 = qoff0 + 32 * 64;
    bf16x8 qfh0[4], qfl0[4], qfh1[4], qfl1[4];
    #pragma unroll
    for (int c = 0; c < 4; ++c) {
        qfh0[c] = *(const bf16x8*)(qh + qoff0 + 16 * c);
        qfl0[c] = *(const bf16x8*)(ql + qoff0 + 16 * c);
        qfh1[c] = *(const bf16x8*)(qh + qoff1 + 16 * c);
        qfl1[c] = *(const bf16x8*)(ql + qoff1 + 16 * c);
    }

    const float nmk = nmaskf[b];
    const char* __restrict__ kvg = kvf + (long)bh * BH_B;

    f32x16 o00 = {}, o01 = {}, o10 = {}, o11 = {};
    float l0 = 0.f, l1 = 0.f;

    // stage: this wave moves fragments wave*3 .. wave*3+2 (3KB) of a tile
    const int fbase = wave * 3 * 1024;

    // prologue: stage tile 0 into buffer 0
    {
        const char* src = kvg + fbase + (long)lane * 16;
        #pragma unroll
        for (int f = 0; f < 3; ++f)
            gload_lds16(src + f * 1024, &kvt[0][fbase + f * 1024]);
    }
    __syncthreads();

    #pragma unroll 1
    for (int it = 0; it < 64; ++it) {
        const int cur = it & 1;
        const int nxt = (it < 63) ? it + 1 : 63;   // last iter: harmless re-stage

        // issue next-tile stage first (overlaps with this iter's compute)
        {
            const char* src = kvg + (long)nxt * TILE_B + fbase + (long)lane * 16;
            #pragma unroll
            for (int f = 0; f < 3; ++f)
                gload_lds16(src + f * 1024, &kvt[cur ^ 1][fbase + f * 1024]);
        }

        // fragment reads from LDS (uniform base + lane*16)
        const char* kb = &kvt[cur][0] + (long)lane * 16;
        bf16x8 kfh[4], kfl[4];
        #pragma unroll
        for (int c = 0; c < 4; ++c) {
            kfh[c] = *(const bf16x8*)(kb + c * 1024);
            kfl[c] = *(const bf16x8*)(kb + 4096 + c * 1024);
        }
        bf16x8 v00 = *(const bf16x8*)(kb + 8192);
        bf16x8 v01 = *(const bf16x8*)(kb + 9216);
        bf16x8 v10 = *(const bf16x8*)(kb + 10240);
        bf16x8 v11 = *(const bf16x8*)(kb + 11264);

        f32x16 s0 = {}, s1 = {};
        __builtin_amdgcn_s_setprio(1);
        #pragma unroll
        for (int c = 0; c < 4; ++c) {
            s0 = mfma32(kfh[c], qfh0[c], s0);
            s1 = mfma32(kfh[c], qfh1[c], s1);
            s0 = mfma32(kfl[c], qfh0[c], s0);
            s1 = mfma32(kfl[c], qfh1[c], s1);
            s0 = mfma32(kfh[c], qfl0[c], s0);
            s1 = mfma32(kfh[c], qfl1[c], s1);
        }
        __builtin_amdgcn_s_setprio(0);

        // tile 0
        {
            float p[16];
            #pragma unroll
            for (int r = 0; r < 16; ++r) {
                float sv = floorf(s0[r]);          // K pre-scaled by 1/8
                p[r] = __expf(sv);
                l0 += p[r];
            }
            bf16x8 pa0, pa1;
            pack_p(p, pa0, pa1);
            __builtin_amdgcn_s_setprio(1);
            o00 = mfma32(pa0, v00, o00);
            o00 = mfma32(pa1, v01, o00);
            o01 = mfma32(pa0, v10, o01);
            o01 = mfma32(pa1, v11, o01);
            __builtin_amdgcn_s_setprio(0);
        }
        // tile 1
        {
            float p[16];
            #pragma unroll
            for (int r = 0; r < 16; ++r) {
                float sv = floorf(s1[r]);
                p[r] = __expf(sv);
                l1 += p[r];
            }
            bf16x8 pa0, pa1;
            pack_p(p, pa0, pa1);
            __builtin_amdgcn_s_setprio(1);
            o10 = mfma32(pa0, v00, o10);
            o10 = mfma32(pa1, v01, o10);
            o11 = mfma32(pa0, v10, o11);
            o11 = mfma32(pa1, v11, o11);
            __builtin_amdgcn_s_setprio(0);
        }

        // drain stage (vmcnt) + all waves done reading kvt[cur]
        __syncthreads();
    }

    // ---- epilogue: write into FC A-fragment layout ----
    const long mtb = ((long)(b * SEQ + q0) >> 5) * MT_B;
    const int  hfo = (col >> 3) & 1;
    const int  job = (col & 7) * 2;
    const int  cf0 = hh * 4 + (col >> 4);        // dims col
    const int  cf1 = cf0 + 2;                    // dims col+32
    // tile 0
    {
        float ltot = l0 + __shfl_xor(l0, 32) - nmk;
        float linv = 1.0f / ltot;
        #pragma unroll
        for (int r = 0; r < 16; ++r) {
            int row = (r & 3) + ((r >> 2) << 3) + 4 * hf;
            float li = __shfl(linv, row);
            long lb = mtb + (long)(row + 32 * hfo) * 16 + job;
            *(unsigned short*)(af + lb + (long)cf0 * 1024) = bfbits(o00[r] * li);
            *(unsigned short*)(af + lb + (long)cf1 * 1024) = bfbits(o01[r] * li);
        }
    }
    // tile 1
    {
        float ltot = l1 + __shfl_xor(l1, 32) - nmk;
        float linv = 1.0f / ltot;
        #pragma unroll
        for (int r = 0; r < 16; ++r) {
            int row = (r & 3) + ((r >> 2) << 3) + 4 * hf;
            float li = __shfl(linv, row);
            long lb = mtb + MT_B + (long)(row + 32 * hfo) * 16 + job;
            *(unsigned short*)(af + lb + (long)cf0 * 1024) = bfbits(o10[r] * li);
            *(unsigned short*)(af + lb + (long)cf1 * 1024) = bfbits(o11[r] * li);
        }
    }
}

// ---------------------------------------------------------------------------
// FC: out[8192,1024] = A @ W^T + bfc with A, W in fragment layout (af, wf).
// Block = 128x128, 4 waves, wave = 64x64 (2x2 32x32 MFMA tiles).
// ---------------------------------------------------------------------------
__global__ __launch_bounds__(256) void fc_kernel(
    const char* __restrict__ af, const char* __restrict__ wf,
    const float* __restrict__ bias, float* __restrict__ out)
{
    const int lane = threadIdx.x & 63;
    const int wave = threadIdx.x >> 6;
    const int col  = lane & 31;
    const int hf   = lane >> 5;
    const int wm   = wave & 1;
    const int wn   = wave >> 1;
    const int m0   = blockIdx.x * 128 + wm * 64;
    const int n0   = blockIdx.y * 128 + wn * 64;

    f32x16 acc[2][2] = {};
    const char* afb = af + (long)(m0 >> 5) * MT_B + (long)lane * 16;
    const char* wfb = wf + (long)(n0 >> 5) * MT_B + (long)lane * 16;

    #pragma unroll 2
    for (int k0 = 0; k0 < EMB; k0 += 16) {
        const long ko = (long)(k0 >> 4) * 1024;
        bf16x8 a0 = *(const bf16x8*)(afb + ko);
        bf16x8 a1 = *(const bf16x8*)(afb + MT_B + ko);
        bf16x8 b0 = *(const bf16x8*)(wfb + ko);
        bf16x8 b1 = *(const bf16x8*)(wfb + MT_B + ko);
        acc[0][0] = mfma32(a0, b0, acc[0][0]);
        acc[0][1] = mfma32(a0, b1, acc[0][1]);
        acc[1][0] = mfma32(a1, b0, acc[1][0]);
        acc[1][1] = mfma32(a1, b1, acc[1][1]);
    }

    const float b0v = bias[n0 + col];
    const float b1v = bias[n0 + 32 + col];
    #pragma unroll
    for (int mt = 0; mt < 2; ++mt) {
        #pragma unroll
        for (int r = 0; r < 16; ++r) {
            int mrow = m0 + mt * 32 + (r & 3) + ((r >> 2) << 3) + 4 * hf;
            out[(long)mrow * EMB + n0 + col]      = acc[mt][0][r] + b0v;
            out[(long)mrow * EMB + n0 + 32 + col] = acc[mt][1][r] + b1v;
        }
    }
}

// ---------------------------------------------------------------------------
extern "C" void kernel_launch(void* const* d_in, const int* in_sizes, int n_in,
                              void* d_out, int out_size, void* d_ws, size_t ws_size,
                              hipStream_t stream)
{
    const float* q    = (const float*)d_in[0];
    const float* k    = (const float*)d_in[1];
    const float* v    = (const float*)d_in[2];
    const int*   mask = (const int*)  d_in[3];
    const float* Wq   = (const float*)d_in[4];
    const float* bq   = (const float*)d_in[5];
    const float* Wk   = (const float*)d_in[6];
    const float* bk   = (const float*)d_in[7];
    const float* Wv   = (const float*)d_in[8];
    const float* bv   = (const float*)d_in[9];
    const float* Wfc  = (const float*)d_in[10];
    const float* bfc  = (const float*)d_in[11];
    float* out = (float*)d_out;

    const long NP = (long)BATCH * HEADS * SEQ * 64;   // 8,388,608 elems
    bf16_t* qhp = (bf16_t*)d_ws;                      // 16MB
    bf16_t* qlp = qhp + NP;                           // 16MB
    char*   kvf = (char*)(qlp + NP);                  // 48MB K/V fragments
    char*   afp = kvf + 64L * BH_B;                   // 16MB A fragments
    char*   wfp = afp + (long)(BATCH * SEQ / 32) * MT_B;  // 2MB W fragments
    float*  nmf = (float*)(wfp + (long)(EMB / 32) * MT_B);

    nmask_kernel<<<BATCH, 256, 0, stream>>>(mask, nmf);
    wconv_kernel<<<(EMB * EMB / 4) / 256, 256, 0, stream>>>(Wfc, wfp, EMB * EMB);

    dim3 gP(2048, 3);
    proj_kernel<<<gP, 256, 0, stream>>>(q, k, v, Wq, bq, Wk, bk, Wv, bv, mask,
                                        qhp, qlp, kvf);

    attn_kernel<<<512, 256, 0, stream>>>(qhp, qlp, kvf, nmf, afp);

    dim3 gC(64, 8);
    fc_kernel<<<gC, 256, 0, stream>>>(afp, wfp, bfc, out);
}